// Round 4
// baseline (1328.148 us; speedup 1.0000x reference)
//
#include <hip/hip_runtime.h>
#include <math.h>

#define N_ROWS 262144
#define KCODES 512
#define DIM 64
#define BLOCK 256            // 1 row per thread; 4 waves/block
#define KTILE 128            // codes per LDS tile (32 KB + pad row)
#define NTILES (KCODES / KTILE)

// Output layout (flat fp32, reference return order):
static const size_t OFF_LOSS = 0;
static const size_t OFF_Q    = 1;
static const size_t OFF_PERP = 1 + (size_t)N_ROWS * DIM;
static const size_t OFF_ENC  = OFF_PERP + 1;
static const size_t OFF_IDX  = OFF_ENC + (size_t)N_ROWS * KCODES;

// Kernel 1: L2-normalize embedding rows into workspace; init scalar outputs.
__global__ __launch_bounds__(64) void vq_prep(const float* __restrict__ emb,
                                              float* __restrict__ embn,
                                              float* __restrict__ out_loss,
                                              float* __restrict__ out_perp) {
    int k = blockIdx.x;
    int d = threadIdx.x;
    float v = emb[k * DIM + d];
    float s = v * v;
    #pragma unroll
    for (int off = 32; off > 0; off >>= 1) s += __shfl_xor(s, off, 64);
    float scale = 1.0f / fmaxf(sqrtf(s), 1e-12f);
    embn[k * DIM + d] = v * scale;
    if (k == 0 && d == 0) {
        *out_loss = 0.0f;
        *out_perp = 1.0f;
    }
}

// Load one 16-float granule (4 x ds_read_b128) into a float4[4] buffer.
#define LOADG(buf, p)                                                          \
    do { buf[0] = (p)[0]; buf[1] = (p)[1]; buf[2] = (p)[2]; buf[3] = (p)[3]; } while (0)

// dot of a 16-float granule with xr[o..o+15], two 8-deep chains.
__device__ __forceinline__ float dot16(const float4* buf, const float* xr, int o) {
    float u, v;
    u = buf[0].x * xr[o + 0];
    u = fmaf(buf[0].y, xr[o + 1], u);
    u = fmaf(buf[0].z, xr[o + 2], u);
    u = fmaf(buf[0].w, xr[o + 3], u);
    u = fmaf(buf[1].x, xr[o + 4], u);
    u = fmaf(buf[1].y, xr[o + 5], u);
    u = fmaf(buf[1].z, xr[o + 6], u);
    u = fmaf(buf[1].w, xr[o + 7], u);
    v = buf[2].x * xr[o + 8];
    v = fmaf(buf[2].y, xr[o + 9],  v);
    v = fmaf(buf[2].z, xr[o + 10], v);
    v = fmaf(buf[2].w, xr[o + 11], v);
    v = fmaf(buf[3].x, xr[o + 12], v);
    v = fmaf(buf[3].y, xr[o + 13], v);
    v = fmaf(buf[3].z, xr[o + 14], v);
    v = fmaf(buf[3].w, xr[o + 15], v);
    return u + v;
}

// Kernel 2: one row per thread. Codebook tiles in LDS; inner loop consumes
// 16-float granules through an explicit 2-buffer register pipeline so every
// ds_read group is issued ~1 granule before its use (DS returns are in-order,
// so the compiler's fine-grained lgkmcnt waits are exact).
__global__ __launch_bounds__(BLOCK, 4) void vq_main(const float* __restrict__ x,
                                                    const int* __restrict__ labels,
                                                    const float* __restrict__ emb,
                                                    const float* __restrict__ embn,
                                                    float* __restrict__ out_loss,
                                                    float* __restrict__ out_q,
                                                    float* __restrict__ out_enc,
                                                    float* __restrict__ out_idx) {
    const int tid   = threadIdx.x;
    const int row   = blockIdx.x * BLOCK + tid;
    const int lane  = tid & 63;
    const int wrow0 = row - lane;                 // first row of this wave

    __shared__ float sE[KTILE * DIM + DIM];       // +1 pad row: pipeline over-read safe
    __shared__ float sLoss[BLOCK / 64];

    // Load this thread's row (contiguous 256 B).
    float xr[DIM];
    {
        const float4* xv = (const float4*)(x + (size_t)row * DIM);
        #pragma unroll
        for (int i = 0; i < DIM / 4; ++i) ((float4*)xr)[i] = xv[i];
    }

    float nx2 = 0.f;
    #pragma unroll
    for (int d = 0; d < DIM; ++d) nx2 = fmaf(xr[d], xr[d], nx2);
    const float inv_nx = 1.0f / fmaxf(sqrtf(nx2), 1e-12f);

    const int lbl = labels[row];

    float best = -3.4e38f;
    int   bidx = 0;
    float pick = 0.f;

    for (int t = 0; t < NTILES; ++t) {
        __syncthreads();
        // Cooperative tile load: 8192 floats; each thread moves 8 float4.
        {
            const float4* src = (const float4*)(embn + (size_t)t * KTILE * DIM);
            float4* dst = (float4*)sE;
            #pragma unroll
            for (int i = 0; i < (KTILE * DIM / 4) / BLOCK; ++i)
                dst[tid + i * BLOCK] = src[tid + i * BLOCK];
        }
        __syncthreads();

        // Streamed zero-fill of encodings cols [t*KTILE, +KTILE) for this
        // wave's 64 rows — overlaps the k-loop's FMA burst.
        {
            float* encb = out_enc + (size_t)wrow0 * KCODES + t * KTILE;
            const int rsub = lane >> 5;           // 0..1
            const int c    = (lane & 31) * 4;
            const float4 z = make_float4(0.f, 0.f, 0.f, 0.f);
            #pragma unroll
            for (int i = 0; i < 32; ++i)
                *(float4*)(encb + (size_t)(i * 2 + rsub) * KCODES + c) = z;
        }

        // Pipelined dot products: bufA/bufB rotate 16-float granules.
        const float4* sEv = (const float4*)sE;
        float4 bufA[4], bufB[4];
        LOADG(bufA, sEv);                         // g0 of kk=0
        const int kbase = t * KTILE;
        for (int kk = 0; kk < KTILE; ++kk) {
            const float4* rowp = sEv + (kk << 4);
            LOADG(bufB, rowp + 4);                // g1 in flight
            float p0 = dot16(bufA, xr, 0);        // consume g0
            LOADG(bufA, rowp + 8);                // g2 in flight
            float p1 = dot16(bufB, xr, 16);       // consume g1
            LOADG(bufB, rowp + 12);               // g3 in flight
            float p2 = dot16(bufA, xr, 32);       // consume g2
            LOADG(bufA, rowp + 16);               // g0 of kk+1 (pad row at end)
            float p3 = dot16(bufB, xr, 48);       // consume g3
            float dot = (p0 + p1) + (p2 + p3);
            int k = kbase + kk;
            if (dot > best) { best = dot; bidx = k; }  // strict > = first max
            pick = (k == lbl) ? dot : pick;
        }
    }

    // quantized = raw embedding row at argmax — wave-cooperative, coalesced
    // (1 KB per store instruction; emb table is 128 KB, L2-resident).
    #pragma unroll
    for (int i = 0; i < 16; ++i) {
        const int r     = i * 4 + (lane >> 4);    // 0..63: row within wave
        const int chunk = lane & 15;              // float4 index within row
        const int bi    = __shfl(bidx, r, 64);
        float4 v = ((const float4*)(emb + (size_t)bi * DIM))[chunk];
        ((float4*)(out_q + (size_t)(wrow0 + r) * DIM))[chunk] = v;
    }

    out_idx[row] = (float)bidx;

    // loss = mean(1 - distances[i, label_i]).
    float lv = (1.0f - pick * inv_nx) * (1.0f / (float)N_ROWS);
    #pragma unroll
    for (int off = 32; off > 0; off >>= 1) lv += __shfl_xor(lv, off, 64);
    if (lane == 0) sLoss[tid >> 6] = lv;
    __syncthreads();
    if (tid == 0) {
        float s = 0.f;
        #pragma unroll
        for (int i = 0; i < BLOCK / 64; ++i) s += sLoss[i];
        atomicAdd(out_loss, s);
    }

    // Ensure this wave's zero-fill stores have completed, then scatter the
    // single 1.0 per row (same wave wrote those zeros; vmcnt orders them).
    asm volatile("s_waitcnt vmcnt(0)" ::: "memory");
    out_enc[(size_t)row * KCODES + bidx] = 1.0f;
}

extern "C" void kernel_launch(void* const* d_in, const int* in_sizes, int n_in,
                              void* d_out, int out_size, void* d_ws, size_t ws_size,
                              hipStream_t stream) {
    const float* x      = (const float*)d_in[0];
    const int*   labels = (const int*)d_in[1];
    const float* emb    = (const float*)d_in[2];
    float* out  = (float*)d_out;
    float* embn = (float*)d_ws;  // 512*64*4 = 128 KB

    hipLaunchKernelGGL(vq_prep, dim3(KCODES), dim3(64), 0, stream,
                       emb, embn, out + OFF_LOSS, out + OFF_PERP);
    hipLaunchKernelGGL(vq_main, dim3(N_ROWS / BLOCK), dim3(BLOCK), 0, stream,
                       x, labels, emb, embn,
                       out + OFF_LOSS, out + OFF_Q, out + OFF_ENC, out + OFF_IDX);
}

// Round 5
// 782.812 us; speedup vs baseline: 1.6966x; 1.6966x over previous
//
#include <hip/hip_runtime.h>
#include <math.h>

#define N_ROWS 262144
#define KCODES 512
#define DIM 64
#define BLOCK 256              // 4 waves x 32 rows = 128 rows/block
#define ROWS_PER_BLOCK 128
#define KTILE 128              // codes staged per LDS tile
#define NSTAGES (KCODES / KTILE)
#define LDS_ROW 72             // 64 + 8 pad bf16 elems = 144 B stride (bank-balanced)
#define PLANE_STRIDE (KTILE * LDS_ROW)   // ushorts

typedef __attribute__((ext_vector_type(8))) short short8;   // 8 bf16 = 4 VGPRs
typedef __attribute__((ext_vector_type(4))) float f4;       // MFMA accumulator

// Output layout (flat fp32, reference return order):
static const size_t OFF_LOSS = 0;
static const size_t OFF_Q    = 1;
static const size_t OFF_PERP = 1 + (size_t)N_ROWS * DIM;
static const size_t OFF_ENC  = OFF_PERP + 1;
static const size_t OFF_IDX  = OFF_ENC + (size_t)N_ROWS * KCODES;

__device__ __forceinline__ unsigned short bf16rne(float f) {
    unsigned int u = __float_as_uint(f);
    u = (u + 0x7fffu + ((u >> 16) & 1u)) >> 16;
    return (unsigned short)u;
}
__device__ __forceinline__ float bf16tof(unsigned short h) {
    return __uint_as_float(((unsigned int)h) << 16);
}

// Kernel 1: L2-normalize embedding rows, 3-way bf16 split into ws planes.
// x ~= h + m + l with 8 mantissa bits each => (h+m+l) matches fp32 to ~2^-26.
__global__ __launch_bounds__(64) void vq_prep(const float* __restrict__ emb,
                                              unsigned short* __restrict__ ph,
                                              unsigned short* __restrict__ pm,
                                              unsigned short* __restrict__ pl,
                                              float* __restrict__ out_loss,
                                              float* __restrict__ out_perp) {
    int k = blockIdx.x;
    int d = threadIdx.x;
    float v = emb[k * DIM + d];
    float s = v * v;
    #pragma unroll
    for (int off = 32; off > 0; off >>= 1) s += __shfl_xor(s, off, 64);
    float vn = v / fmaxf(sqrtf(s), 1e-12f);
    unsigned short h = bf16rne(vn);
    float r = vn - bf16tof(h);
    unsigned short m = bf16rne(r);
    r = r - bf16tof(m);
    unsigned short l = bf16rne(r);
    ph[k * DIM + d] = h;
    pm[k * DIM + d] = m;
    pl[k * DIM + d] = l;
    if (k == 0 && d == 0) { *out_loss = 0.0f; *out_perp = 1.0f; }
}

#define MFMA(A, B, C) C = __builtin_amdgcn_mfma_f32_16x16x32_bf16(A, B, C, 0, 0, 0)

__global__ __launch_bounds__(BLOCK) void vq_main(const float* __restrict__ x,
                                                 const int* __restrict__ labels,
                                                 const float* __restrict__ emb,
                                                 const unsigned short* __restrict__ ph,
                                                 const unsigned short* __restrict__ pm,
                                                 const unsigned short* __restrict__ pl,
                                                 float* __restrict__ out_loss,
                                                 float* __restrict__ out_q,
                                                 float* __restrict__ out_enc,
                                                 float* __restrict__ out_idx) {
    const int tid   = threadIdx.x;
    const int wv    = tid >> 6;
    const int lane  = tid & 63;
    const int q     = lane >> 4;       // quad 0..3
    const int c     = lane & 15;
    const int wbase = blockIdx.x * ROWS_PER_BLOCK + wv * 32;  // wave owns 32 rows

    __shared__ __align__(16) unsigned short sE[3 * PLANE_STRIDE];  // h,m,l planes
    __shared__ int   sIdx[4][32];
    __shared__ float sPick[4][32];
    __shared__ float sInv[4][32];
    __shared__ float sLoss[4];

    // ---- A fragments: lane holds rows (wbase + t*16 + c), k = s*32 + q*8 + j ----
    float xv[2][16];
    #pragma unroll
    for (int t = 0; t < 2; ++t) {
        const float* xp = x + (size_t)(wbase + t * 16 + c) * DIM + q * 8;
        #pragma unroll
        for (int s = 0; s < 2; ++s) {
            float4 lo = *(const float4*)(xp + s * 32);
            float4 hi = *(const float4*)(xp + s * 32 + 4);
            xv[t][s * 8 + 0] = lo.x; xv[t][s * 8 + 1] = lo.y;
            xv[t][s * 8 + 2] = lo.z; xv[t][s * 8 + 3] = lo.w;
            xv[t][s * 8 + 4] = hi.x; xv[t][s * 8 + 5] = hi.y;
            xv[t][s * 8 + 6] = hi.z; xv[t][s * 8 + 7] = hi.w;
        }
    }

    // per-row 1/||x||: lane's 16 elements + quad partners (xor 16, 32)
    float inv_nx[2];
    #pragma unroll
    for (int t = 0; t < 2; ++t) {
        float s2 = 0.f;
        #pragma unroll
        for (int j = 0; j < 16; ++j) s2 = fmaf(xv[t][j], xv[t][j], s2);
        s2 += __shfl_xor(s2, 16, 64);
        s2 += __shfl_xor(s2, 32, 64);
        inv_nx[t] = 1.0f / fmaxf(sqrtf(s2), 1e-12f);
    }

    // 3-way bf16 split of the A fragments (no normalization: argmax-invariant).
    short8 Ah[2][2], Am[2][2], Al[2][2];
    #pragma unroll
    for (int t = 0; t < 2; ++t)
        #pragma unroll
        for (int s = 0; s < 2; ++s)
            #pragma unroll
            for (int j = 0; j < 8; ++j) {
                float v = xv[t][s * 8 + j];
                unsigned short h = bf16rne(v);
                float r = v - bf16tof(h);
                unsigned short m = bf16rne(r);
                r = r - bf16tof(m);
                unsigned short l = bf16rne(r);
                Ah[t][s][j] = (short)h;
                Am[t][s][j] = (short)m;
                Al[t][s][j] = (short)l;
            }

    // labels for this lane's 8 C-rows (rows t*16 + q*4 + r)
    int   lbl[2][4];
    float best[2][4], pick[2][4];
    int   bidx[2][4];
    #pragma unroll
    for (int t = 0; t < 2; ++t)
        #pragma unroll
        for (int r = 0; r < 4; ++r) {
            lbl[t][r]  = labels[wbase + t * 16 + q * 4 + r];
            best[t][r] = -3.4e38f;
            bidx[t][r] = 0;
            pick[t][r] = 0.f;
        }

    for (int st = 0; st < NSTAGES; ++st) {
        __syncthreads();
        // Stage 3 planes of 128 codes: 1024 16B-chunks/plane, 4 per thread.
        #pragma unroll
        for (int i = 0; i < 4; ++i) {
            int ch = tid + i * BLOCK;
            int code = ch >> 3, part = ch & 7;
            int dst = code * LDS_ROW + part * 8;
            int src = st * (KTILE * DIM) + ch * 8;
            *(float4*)&sE[dst]                    = *(const float4*)(ph + src);
            *(float4*)&sE[PLANE_STRIDE + dst]     = *(const float4*)(pm + src);
            *(float4*)&sE[2 * PLANE_STRIDE + dst] = *(const float4*)(pl + src);
        }
        __syncthreads();

        #pragma unroll 2
        for (int sub = 0; sub < KTILE / 16; ++sub) {
            // B frags: lane holds code (sub*16+c), k = s*32 + q*8 + j — contiguous 16B.
            const unsigned short* bp = &sE[(sub * 16 + c) * LDS_ROW + q * 8];
            short8 Bh0 = *(const short8*)(bp);
            short8 Bh1 = *(const short8*)(bp + 32);
            short8 Bm0 = *(const short8*)(bp + PLANE_STRIDE);
            short8 Bm1 = *(const short8*)(bp + PLANE_STRIDE + 32);
            short8 Bl0 = *(const short8*)(bp + 2 * PLANE_STRIDE);
            short8 Bl1 = *(const short8*)(bp + 2 * PLANE_STRIDE + 32);

            f4 acc0 = {0.f, 0.f, 0.f, 0.f};
            f4 acc1 = {0.f, 0.f, 0.f, 0.f};
            // 6 split-products x 2 K-steps, both M-tiles (B reused 2x).
            MFMA(Ah[0][0], Bh0, acc0);  MFMA(Ah[1][0], Bh0, acc1);
            MFMA(Ah[0][1], Bh1, acc0);  MFMA(Ah[1][1], Bh1, acc1);
            MFMA(Ah[0][0], Bm0, acc0);  MFMA(Ah[1][0], Bm0, acc1);
            MFMA(Ah[0][1], Bm1, acc0);  MFMA(Ah[1][1], Bm1, acc1);
            MFMA(Am[0][0], Bh0, acc0);  MFMA(Am[1][0], Bh0, acc1);
            MFMA(Am[0][1], Bh1, acc0);  MFMA(Am[1][1], Bh1, acc1);
            MFMA(Ah[0][0], Bl0, acc0);  MFMA(Ah[1][0], Bl0, acc1);
            MFMA(Ah[0][1], Bl1, acc0);  MFMA(Ah[1][1], Bl1, acc1);
            MFMA(Al[0][0], Bh0, acc0);  MFMA(Al[1][0], Bh0, acc1);
            MFMA(Al[0][1], Bh1, acc0);  MFMA(Al[1][1], Bh1, acc1);
            MFMA(Am[0][0], Bm0, acc0);  MFMA(Am[1][0], Bm0, acc1);
            MFMA(Am[0][1], Bm1, acc0);  MFMA(Am[1][1], Bm1, acc1);

            const int code = st * KTILE + sub * 16 + c;  // this lane's column
            #pragma unroll
            for (int r = 0; r < 4; ++r) {
                float d0 = acc0[r];
                if (d0 > best[0][r]) { best[0][r] = d0; bidx[0][r] = code; }
                if (code == lbl[0][r]) pick[0][r] = d0;
                float d1 = acc1[r];
                if (d1 > best[1][r]) { best[1][r] = d1; bidx[1][r] = code; }
                if (code == lbl[1][r]) pick[1][r] = d1;
            }
        }
    }

    // Cross-lane argmax reduce within 16-lane col groups (tie -> smaller idx
    // = first max, matching jnp.argmax); pick is one-hot so sum-reduce.
    #pragma unroll
    for (int t = 0; t < 2; ++t)
        #pragma unroll
        for (int r = 0; r < 4; ++r) {
            float b = best[t][r]; int i = bidx[t][r]; float p = pick[t][r];
            #pragma unroll
            for (int m = 1; m < 16; m <<= 1) {
                float ob = __shfl_xor(b, m, 64);
                int   oi = __shfl_xor(i, m, 64);
                p += __shfl_xor(p, m, 64);
                if (ob > b || (ob == b && oi < i)) { b = ob; i = oi; }
            }
            bidx[t][r] = i; pick[t][r] = p;
        }

    if (c == 0) {
        #pragma unroll
        for (int t = 0; t < 2; ++t)
            #pragma unroll
            for (int r = 0; r < 4; ++r) {
                int rl = t * 16 + q * 4 + r;
                sIdx[wv][rl]  = bidx[t][r];
                sPick[wv][rl] = pick[t][r];
            }
    }
    if (q == 0) { sInv[wv][c] = inv_nx[0]; sInv[wv][16 + c] = inv_nx[1]; }
    __syncthreads();

    // one-hot rows: full-line coalesced float4 stores, 1.0 embedded.
    {
        const int col0 = lane * 4, col1 = 256 + lane * 4;
        for (int r = 0; r < 32; ++r) {
            int bi = sIdx[wv][r];
            float* base = out_enc + (size_t)(wbase + r) * KCODES;
            float4 v0 = make_float4(bi == col0     ? 1.f : 0.f,
                                    bi == col0 + 1 ? 1.f : 0.f,
                                    bi == col0 + 2 ? 1.f : 0.f,
                                    bi == col0 + 3 ? 1.f : 0.f);
            *(float4*)(base + col0) = v0;
            float4 v1 = make_float4(bi == col1     ? 1.f : 0.f,
                                    bi == col1 + 1 ? 1.f : 0.f,
                                    bi == col1 + 2 ? 1.f : 0.f,
                                    bi == col1 + 3 ? 1.f : 0.f);
            *(float4*)(base + col1) = v1;
        }
    }

    // quantized = raw emb row at argmax; 4 rows per pass, coalesced.
    #pragma unroll
    for (int i = 0; i < 8; ++i) {
        int r  = i * 4 + q;
        int bi = sIdx[wv][r];
        float4 v = ((const float4*)(emb + (size_t)bi * DIM))[c];
        ((float4*)(out_q + (size_t)(wbase + r) * DIM))[c] = v;
    }

    if (lane < 32) out_idx[wbase + lane] = (float)sIdx[wv][lane];

    // loss = mean(1 - dist[i, label_i]); dist = split-dot * inv_nx.
    float lv = 0.f;
    if (lane < 32)
        lv = (1.0f - sPick[wv][lane] * sInv[wv][lane]) * (1.0f / (float)N_ROWS);
    #pragma unroll
    for (int m = 1; m < 64; m <<= 1) lv += __shfl_xor(lv, m, 64);
    if (lane == 0) sLoss[wv] = lv;
    __syncthreads();
    if (tid == 0)
        atomicAdd(out_loss, sLoss[0] + sLoss[1] + sLoss[2] + sLoss[3]);
}

extern "C" void kernel_launch(void* const* d_in, const int* in_sizes, int n_in,
                              void* d_out, int out_size, void* d_ws, size_t ws_size,
                              hipStream_t stream) {
    const float* x      = (const float*)d_in[0];
    const int*   labels = (const int*)d_in[1];
    const float* emb    = (const float*)d_in[2];
    float* out = (float*)d_out;
    unsigned short* ph = (unsigned short*)d_ws;              // 64 KB
    unsigned short* pm = ph + (size_t)KCODES * DIM;          // 64 KB
    unsigned short* pl = pm + (size_t)KCODES * DIM;          // 64 KB (192 KB total)

    hipLaunchKernelGGL(vq_prep, dim3(KCODES), dim3(64), 0, stream,
                       emb, ph, pm, pl, out + OFF_LOSS, out + OFF_PERP);
    hipLaunchKernelGGL(vq_main, dim3(N_ROWS / ROWS_PER_BLOCK), dim3(BLOCK), 0, stream,
                       x, labels, emb, ph, pm, pl,
                       out + OFF_LOSS, out + OFF_Q, out + OFF_ENC, out + OFF_IDX);
}